// Round 1
// baseline (294.071 us; speedup 1.0000x reference)
//
#include <hip/hip_runtime.h>
#include <hip/hip_bf16.h>
#include <stdint.h>

// WarpNet: conv_bn_relu(512->384 combined) -> window-distance softmax -> warp -> 1x1 conv -> log_softmax
// All heavy compute (58 GFLOP) in bf16 MFMA implicit-GEMM conv.

typedef float v4f __attribute__((ext_vector_type(4)));
typedef __bf16 v8bf __attribute__((ext_vector_type(8)));
typedef unsigned short u16;
typedef unsigned int u32;
typedef u16 u16x8 __attribute__((ext_vector_type(8)));

// ---------------- workspace layout (bytes) ----------------
constexpr size_t XH_OFF  = 0;                                  // padded NHWC input bf16 [4][66][66][512]
constexpr size_t XH_BYTES = (size_t)4*66*66*512*2;
constexpr size_t WT_OFF  = XH_OFF + XH_BYTES;                  // weights bf16 [9][384][512]
constexpr size_t WT_BYTES = (size_t)9*384*512*2;
constexpr size_t FS_OFF  = WT_OFF + WT_BYTES;                  // clip_emb_s NHWC bf16 [4][68][68][256] (pad2)
constexpr size_t FS_BYTES = (size_t)4*68*68*256*2;
constexpr size_t F2_OFF  = FS_OFF + FS_BYTES;                  // clip_emb2 NHWC f32 [4][68][68][128] (pad2)
constexpr size_t F2_BYTES = (size_t)4*68*68*128*4;
constexpr size_t Y2_OFF  = F2_OFF + F2_BYTES;                  // y2 f32 [2][68][68] (pad=1e20)
constexpr size_t Y2_BYTES = (size_t)2*68*68*4;
constexpr size_t WG_OFF  = Y2_OFF + Y2_BYTES;                  // softmax weights f32 [2][64][64][25]
constexpr size_t WG_BYTES = (size_t)2*64*64*25*4;
constexpr size_t FEA_OFF = WG_OFF + WG_BYTES;                  // final_fea bf16 [2][4096][256]
constexpr size_t FEA_BYTES = (size_t)2*4096*256*2;
constexpr size_t WL_OFF  = FEA_OFF + FEA_BYTES;                // last_W bf16 [128][256] (pad rows 124..127 = 0)
constexpr size_t WL_BYTES = (size_t)128*256*2;
constexpr size_t SC_OFF  = WL_OFF + WL_BYTES;                  // sc[384], bi[384] f32
constexpr size_t WS_TOTAL = SC_OFF + 768*4;

__device__ __forceinline__ float bf2f(u16 h) { return __uint_as_float(((u32)h) << 16); }
__device__ __forceinline__ u16 f2bf(float f) {
  u32 u = __float_as_uint(f);
  return (u16)((u + 0x7fffu + ((u >> 16) & 1u)) >> 16);
}

__device__ __forceinline__ void gld16(const void* g, const void* l) {
  __builtin_amdgcn_global_load_lds(
      (const __attribute__((address_space(1))) void*)(uintptr_t)g,
      (__attribute__((address_space(3))) void*)(u32)(uintptr_t)l,
      16, 0, 0);
}

// ---------------- init: zero padded arrays, Y2 = 1e20 ----------------
__global__ void k_zero(uint4* __restrict__ xh, uint4* __restrict__ fsf2, float4* __restrict__ y2) {
  const u32 NX = (u32)(XH_BYTES / 16);
  const u32 NF = (u32)((FS_BYTES + F2_BYTES) / 16);
  const u32 NY = (u32)(Y2_BYTES / 16);
  const uint4 z = {0u, 0u, 0u, 0u};
  const float4 big = {1e20f, 1e20f, 1e20f, 1e20f};
  for (u32 i = blockIdx.x * 256u + threadIdx.x; i < NX + NF + NY; i += gridDim.x * 256u) {
    if (i < NX) xh[i] = z;
    else if (i < NX + NF) fsf2[i - NX] = z;
    else y2[i - NX - NF] = big;
  }
}

// ---------------- BN fold + last_W pad/cast ----------------
__global__ void k_params(const float* __restrict__ eg, const float* __restrict__ eb,
                         const float* __restrict__ em, const float* __restrict__ ev,
                         const float* __restrict__ e2g, const float* __restrict__ e2b,
                         const float* __restrict__ e2m, const float* __restrict__ e2v,
                         const float* __restrict__ lw,
                         float* __restrict__ sc, float* __restrict__ bi, u16* __restrict__ Wl) {
  const int id = blockIdx.x * 256 + threadIdx.x;
  if (id < 384) {
    float g, b, m, v;
    if (id < 256) { g = eg[id]; b = eb[id]; m = em[id]; v = ev[id]; }
    else { int j = id - 256; g = e2g[j]; b = e2b[j]; m = e2m[j]; v = e2v[j]; }
    const float s = g / sqrtf(v + 1e-5f);
    sc[id] = s;
    bi[id] = b - m * s;
  }
  for (int i = id; i < 128 * 256; i += (int)gridDim.x * 256) {
    const int row = i >> 8, c = i & 255;
    Wl[i] = f2bf(row < 124 ? lw[row * 256 + c] : 0.0f);
  }
}

// ---------------- NCHW f32 -> padded NHWC bf16 ----------------
__global__ __launch_bounds__(256) void k_prep_x(const float* __restrict__ X, u16* __restrict__ Xh) {
  __shared__ __align__(16) float tile[64 * 65];
  const int tid = threadIdx.x;
  const int n = blockIdx.x >> 6, h = blockIdx.x & 63;
  const int wq = tid >> 6, wcol = tid & 63;
  #pragma unroll 1
  for (int c0 = 0; c0 < 512; c0 += 64) {
    __syncthreads();
    #pragma unroll
    for (int i = 0; i < 16; ++i) {
      const int cl = i * 4 + wq;
      tile[cl * 65 + wcol] = X[((size_t)(n * 512 + c0 + cl)) * 4096 + h * 64 + wcol];
    }
    __syncthreads();
    const int w = tid >> 2, cg = tid & 3;
    u16x8 a, b;
    #pragma unroll
    for (int j = 0; j < 8; ++j) a[j] = f2bf(tile[(cg * 16 + j) * 65 + w]);
    #pragma unroll
    for (int j = 0; j < 8; ++j) b[j] = f2bf(tile[(cg * 16 + 8 + j) * 65 + w]);
    u16* dst = Xh + ((size_t)((n * 66 + h + 1) * 66 + (w + 1))) * 512 + c0 + cg * 16;
    *(u16x8*)dst = a;
    *((u16x8*)dst + 1) = b;
  }
}

// ---------------- weights [oc][c][3][3] f32 -> [pos][oc][c] bf16 ----------------
__global__ __launch_bounds__(256) void k_prep_w(const float* __restrict__ embW, const float* __restrict__ emb2W,
                                                u16* __restrict__ Wt) {
  __shared__ float row[4608];
  const int oc = blockIdx.x;
  const int tid = threadIdx.x;
  const float* src = (oc < 256) ? (embW + (size_t)oc * 4608) : (emb2W + (size_t)(oc - 256) * 4608);
  for (int i = tid; i < 4608; i += 256) row[i] = src[i];
  __syncthreads();
  #pragma unroll
  for (int pos = 0; pos < 9; ++pos) {
    const u32 pk = (u32)f2bf(row[(2 * tid) * 9 + pos]) | ((u32)f2bf(row[(2 * tid + 1) * 9 + pos]) << 16);
    *(u32*)(Wt + ((size_t)(pos * 384 + oc)) * 512 + 2 * tid) = pk;
  }
}

// ---------------- implicit-GEMM conv + BN + ReLU ----------------
// grid 384: octile(3) x n(4) x pixtile(32).  tile = 128 oc x (2 rows x 64 w) pixels.
__global__ __launch_bounds__(256) void k_conv(const u16* __restrict__ Xh, const u16* __restrict__ Wt,
                                              const float* __restrict__ sc, const float* __restrict__ bi,
                                              float* __restrict__ out2, float* __restrict__ F2,
                                              u16* __restrict__ Fs) {
  __shared__ __align__(16) char lds[51200];  // A:2x8192 | B:2x16896 @16384 | sc/bi 1KB @50176
  const int tid = threadIdx.x;
  const int wvi = tid >> 6, lane = tid & 63;
  const int bid = blockIdx.x;
  const int octile = bid % 3;
  const int rest = bid / 3;
  const int n = rest & 3, pixtile = rest >> 2;
  const int h0 = pixtile * 2;
  const int oc0 = octile * 128;
  const int whm = wvi >> 1, whn = wvi & 1;

  if (tid < 128) {
    ((float*)(lds + 50176))[tid] = sc[oc0 + tid];
    ((float*)(lds + 50176))[128 + tid] = bi[oc0 + tid];
  }

  auto stageA = [&](int pos, int cc, int buf) {
    #pragma unroll
    for (int i = 0; i < 2; ++i) {
      const char* dst = lds + buf * 8192 + i * 4096 + wvi * 1024;
      const int oc = i * 64 + wvi * 16 + (lane >> 2);
      gld16(Wt + ((size_t)(pos * 384 + oc0 + oc)) * 512 + cc * 32 + (lane & 3) * 8, dst);
    }
  };
  auto stageB = [&](int cc, int buf) {
    const char* rowbase = lds + 16384 + buf * 16896 + wvi * 4224;
    const u16* grow = Xh + ((size_t)((n * 66 + h0 + wvi) * 66)) * 512 + cc * 32;
    #pragma unroll
    for (int i = 0; i < 4; ++i) {
      const int col = i * 16 + (lane >> 2);
      gld16(grow + (size_t)col * 512 + (lane & 3) * 8, rowbase + i * 1024);
    }
    if (lane < 8) {
      const int col = 64 + (lane >> 2);
      gld16(grow + (size_t)col * 512 + (lane & 3) * 8, rowbase + 4096);
    }
  };

  v4f acc[4][4];
  #pragma unroll
  for (int mt = 0; mt < 4; ++mt)
    #pragma unroll
    for (int nt = 0; nt < 4; ++nt) acc[mt][nt] = (v4f){0.f, 0.f, 0.f, 0.f};

  int bA = 0, bB = 0;
  stageB(0, 0);
  stageA(0, 0, 0);
  __syncthreads();

  #pragma unroll 1
  for (int cc = 0; cc < 16; ++cc) {
    #pragma unroll
    for (int pos = 0; pos < 9; ++pos) {
      const int ky = pos / 3, kx = pos % 3;
      if (pos < 8) {
        stageA(pos + 1, cc, bA ^ 1);
      } else if (cc < 15) {
        stageB(cc + 1, bB ^ 1);
        stageA(0, cc + 1, bA ^ 1);
      }
      v8bf af[4], bfr[4];
      const char* pA = lds + bA * 8192 + ((lane & 15) + whm * 64) * 64 + (lane >> 4) * 16;
      const char* pB = lds + 16384 + bB * 16896 + ((whn + ky) * 66 + kx + (lane & 15)) * 64 + (lane >> 4) * 16;
      #pragma unroll
      for (int mt = 0; mt < 4; ++mt) af[mt] = *(const v8bf*)(pA + mt * 1024);
      #pragma unroll
      for (int nt = 0; nt < 4; ++nt) bfr[nt] = *(const v8bf*)(pB + nt * 1024);
      #pragma unroll
      for (int mt = 0; mt < 4; ++mt)
        #pragma unroll
        for (int nt = 0; nt < 4; ++nt)
          acc[mt][nt] = __builtin_amdgcn_mfma_f32_16x16x32_bf16(af[mt], bfr[nt], acc[mt][nt], 0, 0, 0);
      __syncthreads();
      bA ^= 1;
      if (pos == 8) bB ^= 1;
    }
  }

  // BN + ReLU
  const float* scl = (const float*)(lds + 50176);
  const float* bil = scl + 128;
  float vals[4][4][4];
  #pragma unroll
  for (int mt = 0; mt < 4; ++mt) {
    const int ocb = whm * 64 + mt * 16 + (lane >> 4) * 4;
    #pragma unroll
    for (int j = 0; j < 4; ++j) {
      const float s = scl[ocb + j], tt = bil[ocb + j];
      #pragma unroll
      for (int nt = 0; nt < 4; ++nt) vals[mt][nt][j] = fmaxf(fmaf(acc[mt][nt][j], s, tt), 0.f);
    }
  }

  if (octile == 2) {
    // emb2: NCHW f32 to d_out (direct) + NHWC f32 to F2 (LDS transpose)
    #pragma unroll
    for (int mt = 0; mt < 4; ++mt)
      #pragma unroll
      for (int j = 0; j < 4; ++j) {
        const int oc = whm * 64 + mt * 16 + (lane >> 4) * 4 + j;
        float* orow = out2 + ((size_t)(n * 128 + oc)) * 4096 + (h0 + whn) * 64;
        #pragma unroll
        for (int nt = 0; nt < 4; ++nt) orow[nt * 16 + (lane & 15)] = vals[mt][nt][j];
      }
    float* T = (float*)lds;
    #pragma unroll 1
    for (int mr = 0; mr < 2; ++mr) {
      __syncthreads();
      if (whm == mr) {
        #pragma unroll
        for (int mt = 0; mt < 4; ++mt)
          #pragma unroll
          for (int nt = 0; nt < 4; ++nt)
            #pragma unroll
            for (int j = 0; j < 4; ++j)
              T[(whn * 64 + nt * 16 + (lane & 15)) * 64 + mt * 16 + (lane >> 4) * 4 + j] = vals[mt][nt][j];
      }
      __syncthreads();
      const int px = tid >> 1, q = tid & 1;
      const float4* Tp = (const float4*)(T + px * 64 + q * 32);
      float4* dst = (float4*)(F2 + ((size_t)((n * 68 + h0 + (px >> 6) + 2) * 68 + (px & 63) + 2)) * 128 + mr * 64 + q * 32);
      #pragma unroll
      for (int i = 0; i < 8; ++i) dst[i] = Tp[i];
    }
  } else {
    // emb: NHWC bf16 to Fs (LDS transpose)
    u16* T = (u16*)lds;
    #pragma unroll 1
    for (int mr = 0; mr < 2; ++mr) {
      __syncthreads();
      if (whm == mr) {
        #pragma unroll
        for (int mt = 0; mt < 4; ++mt)
          #pragma unroll
          for (int nt = 0; nt < 4; ++nt)
            #pragma unroll
            for (int jj = 0; jj < 2; ++jj) {
              const u32 pk = (u32)f2bf(vals[mt][nt][2 * jj]) | ((u32)f2bf(vals[mt][nt][2 * jj + 1]) << 16);
              *(u32*)(T + (whn * 64 + nt * 16 + (lane & 15)) * 64 + mt * 16 + (lane >> 4) * 4 + 2 * jj) = pk;
            }
      }
      __syncthreads();
      const int px = tid >> 1, q = tid & 1;
      const u16x8* Tp = (const u16x8*)(T + px * 64 + q * 32);
      u16x8* dst = (u16x8*)(Fs + ((size_t)((n * 68 + h0 + (px >> 6) + 2) * 68 + (px & 63) + 2)) * 256 + octile * 128 + mr * 64 + q * 32);
      #pragma unroll
      for (int i = 0; i < 4; ++i) dst[i] = Tp[i];
    }
  }
}

// ---------------- y2 = sum_c F2^2 (images 0,1) ----------------
__global__ __launch_bounds__(256) void k_y2(const float* __restrict__ F2, float* __restrict__ Y2) {
  const int n = blockIdx.x >> 6, row = blockIdx.x & 63;
  const int t = threadIdx.x;
  const int w = t >> 2, q = t & 3;
  const float4* p = (const float4*)(F2 + ((size_t)((n * 68 + row + 2) * 68 + (w + 2))) * 128 + q * 32);
  float s = 0.f;
  #pragma unroll
  for (int i = 0; i < 8; ++i) { float4 v = p[i]; s += v.x * v.x + v.y * v.y + v.z * v.z + v.w * v.w; }
  s += __shfl_xor(s, 1);
  s += __shfl_xor(s, 2);
  if (q == 0) Y2[(n * 68 + row + 2) * 68 + (w + 2)] = s;
}

// ---------------- distance + softmax over 25 offsets ----------------
__global__ __launch_bounds__(128) void k_dist(const float* __restrict__ F2, const float* __restrict__ Y2,
                                              float* __restrict__ Wg) {
  __shared__ __align__(16) float win[6 * 68 * 32];
  const int n = blockIdx.x >> 5, h0 = (blockIdx.x & 31) * 2;
  const int t = threadIdx.x;
  const int r = t >> 6, w = t & 63;
  float cross[25];
  #pragma unroll
  for (int o = 0; o < 25; ++o) cross[o] = 0.f;
  float x2 = 0.f;
  #pragma unroll 1
  for (int cc = 0; cc < 4; ++cc) {
    __syncthreads();
    for (int idx = t; idx < 6 * 68 * 8; idx += 128) {
      const int row = idx / 544, rem = idx - row * 544;
      const int col = rem >> 3, c4 = rem & 7;
      ((float4*)win)[idx] = *(const float4*)(F2 + ((size_t)((n * 68 + h0 + row) * 68 + col)) * 128 + cc * 32 + c4 * 4);
    }
    __syncthreads();
    const float4* c2p = (const float4*)(F2 + ((size_t)(((n + 2) * 68 + h0 + r + 2) * 68 + (w + 2))) * 128 + cc * 32);
    float4 c2v[8];
    #pragma unroll
    for (int i = 0; i < 8; ++i) {
      c2v[i] = c2p[i];
      x2 += c2v[i].x * c2v[i].x + c2v[i].y * c2v[i].y + c2v[i].z * c2v[i].z + c2v[i].w * c2v[i].w;
    }
    #pragma unroll
    for (int dy = 0; dy < 5; ++dy)
      #pragma unroll
      for (int dx = 0; dx < 5; ++dx) {
        const float4* wp = (const float4*)(win + ((r + dy) * 68 + (w + dx)) * 32);
        float sA = 0.f;
        #pragma unroll
        for (int i = 0; i < 8; ++i) {
          float4 u = wp[i];
          sA += c2v[i].x * u.x + c2v[i].y * u.y + c2v[i].z * u.z + c2v[i].w * u.w;
        }
        cross[dy * 5 + dx] += sA;
      }
  }
  float logit[25], mx = -1e30f;
  #pragma unroll
  for (int dy = 0; dy < 5; ++dy)
    #pragma unroll
    for (int dx = 0; dx < 5; ++dx) {
      const int o = dy * 5 + dx;
      const float y2v = Y2[(n * 68 + h0 + r + dy) * 68 + (w + dx)];
      const float dist = x2 + y2v - 2.f * cross[o];
      const float l = 1.f / (dist + 1e-5f);
      logit[o] = l;
      mx = fmaxf(mx, l);
    }
  float ssum = 0.f;
  #pragma unroll
  for (int o = 0; o < 25; ++o) { const float e = __expf(logit[o] - mx); logit[o] = e; ssum += e; }
  const float inv = 1.f / ssum;
  float* dst = Wg + ((size_t)(n * 4096 + (h0 + r) * 64 + w)) * 25;
  #pragma unroll
  for (int o = 0; o < 25; ++o) dst[o] = logit[o] * inv;
}

// ---------------- warp + combine -> fea bf16 ----------------
__global__ __launch_bounds__(128) void k_warp(const u16* __restrict__ Fs, const float* __restrict__ Wg,
                                              u16* __restrict__ Fea) {
  __shared__ __align__(16) float win[6 * 68 * 32];
  const int cq = blockIdx.x & 3;
  const int hp = (blockIdx.x >> 2) & 31;
  const int n = blockIdx.x >> 7;
  const int h0 = hp * 2;
  const int t = threadIdx.x;
  const int r = t >> 6, w = t & 63;
  float wv[25];
  {
    const float* wgp = Wg + ((size_t)(n * 4096 + (h0 + r) * 64 + w)) * 25;
    #pragma unroll
    for (int o = 0; o < 25; ++o) wv[o] = wgp[o];
  }
  #pragma unroll 1
  for (int ci = 0; ci < 2; ++ci) {
    const int cc = cq * 2 + ci;
    __syncthreads();
    for (int idx = t; idx < 6 * 68 * 4; idx += 128) {
      const int row = idx / 272, rem = idx - row * 272;
      const int col = rem >> 2, c8 = rem & 3;
      u16x8 u = *(const u16x8*)(Fs + ((size_t)((n * 68 + h0 + row) * 68 + col)) * 256 + cc * 32 + c8 * 8);
      float* wd = win + (row * 68 + col) * 32 + c8 * 8;
      float4 lo = {bf2f(u[0]), bf2f(u[1]), bf2f(u[2]), bf2f(u[3])};
      float4 hi = {bf2f(u[4]), bf2f(u[5]), bf2f(u[6]), bf2f(u[7])};
      *(float4*)wd = lo;
      *(float4*)(wd + 4) = hi;
    }
    __syncthreads();
    float facc[32];
    #pragma unroll
    for (int i = 0; i < 32; ++i) facc[i] = 0.f;
    #pragma unroll
    for (int dy = 0; dy < 5; ++dy)
      #pragma unroll
      for (int dx = 0; dx < 5; ++dx) {
        const float wt = wv[dy * 5 + dx];
        const float* wp = win + ((r + dy) * 68 + (w + dx)) * 32;
        #pragma unroll
        for (int i = 0; i < 32; ++i) facc[i] = fmaf(wt, wp[i], facc[i]);
      }
    const u16* cp = Fs + ((size_t)(((n + 2) * 68 + h0 + r + 2) * 68 + (w + 2))) * 256 + cc * 32;
    u16* dp = Fea + ((size_t)(n * 4096 + (h0 + r) * 64 + w)) * 256 + cc * 32;
    #pragma unroll
    for (int g = 0; g < 4; ++g) {
      u16x8 cu = *(const u16x8*)(cp + g * 8);
      u16x8 ou;
      #pragma unroll
      for (int k = 0; k < 8; ++k) {
        const float f = 0.5f * (bf2f(cu[k]) + facc[g * 8 + k] * (1.f / 25.f));
        ou[k] = f2bf(f);
      }
      *(u16x8*)(dp + g * 8) = ou;
    }
  }
}

// ---------------- logits (124x256 matvec via MFMA) + log_softmax ----------------
__global__ __launch_bounds__(256) void k_logits(const u16* __restrict__ Fea, const u16* __restrict__ Wl,
                                                const float* __restrict__ lb, float* __restrict__ xout) {
  const int tid = threadIdx.x;
  const int wvi = tid >> 6, lane = tid & 63;
  const int img = blockIdx.x >> 5, pt = blockIdx.x & 31;
  const int pxb = img * 4096 + pt * 128 + wvi * 32;
  const int kb = (lane >> 4) * 8;
  const int lp = lane & 15;

  v4f acc[8][2];
  #pragma unroll
  for (int mt = 0; mt < 8; ++mt) { acc[mt][0] = (v4f){0.f,0.f,0.f,0.f}; acc[mt][1] = (v4f){0.f,0.f,0.f,0.f}; }

  #pragma unroll
  for (int kc = 0; kc < 8; ++kc) {
    v8bf b0 = *(const v8bf*)(Fea + ((size_t)(pxb + lp)) * 256 + kc * 32 + kb);
    v8bf b1 = *(const v8bf*)(Fea + ((size_t)(pxb + 16 + lp)) * 256 + kc * 32 + kb);
    #pragma unroll
    for (int mt = 0; mt < 8; ++mt) {
      v8bf a = *(const v8bf*)(Wl + ((size_t)(mt * 16 + lp)) * 256 + kc * 32 + kb);
      acc[mt][0] = __builtin_amdgcn_mfma_f32_16x16x32_bf16(a, b0, acc[mt][0], 0, 0, 0);
      acc[mt][1] = __builtin_amdgcn_mfma_f32_16x16x32_bf16(a, b1, acc[mt][1], 0, 0, 0);
    }
  }
  const int r0 = (lane >> 4) * 4;
  #pragma unroll
  for (int nt = 0; nt < 2; ++nt) {
    float v[8][4];
    float mx = -1e30f;
    #pragma unroll
    for (int mt = 0; mt < 8; ++mt)
      #pragma unroll
      for (int j = 0; j < 4; ++j) {
        const int cls = mt * 16 + r0 + j;
        const float val = (cls < 124) ? (acc[mt][nt][j] + lb[cls]) : -1e30f;
        v[mt][j] = val;
        mx = fmaxf(mx, val);
      }
    mx = fmaxf(mx, __shfl_xor(mx, 16));
    mx = fmaxf(mx, __shfl_xor(mx, 32));
    float s = 0.f;
    #pragma unroll
    for (int mt = 0; mt < 8; ++mt)
      #pragma unroll
      for (int j = 0; j < 4; ++j) {
        const int cls = mt * 16 + r0 + j;
        if (cls < 124) s += __expf(v[mt][j] - mx);
      }
    s += __shfl_xor(s, 16);
    s += __shfl_xor(s, 32);
    const float lz = mx + logf(s);
    #pragma unroll
    for (int mt = 0; mt < 8; ++mt)
      #pragma unroll
      for (int j = 0; j < 4; ++j) {
        const int cls = mt * 16 + r0 + j;
        if (cls < 124)
          xout[((size_t)(img * 124 + cls)) * 4096 + pt * 128 + wvi * 32 + nt * 16 + lp] = v[mt][j] - lz;
      }
  }
}

extern "C" void kernel_launch(void* const* d_in, const int* in_sizes, int n_in,
                              void* d_out, int out_size, void* d_ws, size_t ws_size,
                              hipStream_t stream) {
  (void)in_sizes; (void)n_in; (void)out_size;
  const float* clip  = (const float*)d_in[0];
  const float* embW  = (const float*)d_in[2];
  const float* eg    = (const float*)d_in[3];
  const float* eb    = (const float*)d_in[4];
  const float* em    = (const float*)d_in[5];
  const float* ev    = (const float*)d_in[6];
  const float* emb2W = (const float*)d_in[7];
  const float* e2g   = (const float*)d_in[8];
  const float* e2b   = (const float*)d_in[9];
  const float* e2m   = (const float*)d_in[10];
  const float* e2v   = (const float*)d_in[11];
  const float* lw    = (const float*)d_in[12];
  const float* lb    = (const float*)d_in[13];

  char* ws = (char*)d_ws;
  u16*   Xh  = (u16*)(ws + XH_OFF);
  u16*   Wt  = (u16*)(ws + WT_OFF);
  u16*   Fs  = (u16*)(ws + FS_OFF);
  float* F2  = (float*)(ws + F2_OFF);
  float* Y2  = (float*)(ws + Y2_OFF);
  float* Wg  = (float*)(ws + WG_OFF);
  u16*   Fea = (u16*)(ws + FEA_OFF);
  u16*   Wl  = (u16*)(ws + WL_OFF);
  float* sc  = (float*)(ws + SC_OFF);
  float* bi  = sc + 384;

  float* xout = (float*)d_out;
  float* out2 = xout + (size_t)2 * 124 * 64 * 64;

  if (ws_size < WS_TOTAL) return;  // workspace too small -> visible failure

  k_zero<<<2048, 256, 0, stream>>>((uint4*)Xh, (uint4*)Fs, (float4*)Y2);
  k_params<<<128, 256, 0, stream>>>(eg, eb, em, ev, e2g, e2b, e2m, e2v, lw, sc, bi, Wl);
  k_prep_x<<<256, 256, 0, stream>>>(clip, Xh);
  k_prep_w<<<384, 256, 0, stream>>>(embW, emb2W, Wt);
  k_conv<<<384, 256, 0, stream>>>(Xh, Wt, sc, bi, out2, F2, Fs);
  k_y2<<<128, 256, 0, stream>>>(F2, Y2);
  k_dist<<<64, 128, 0, stream>>>(F2, Y2, Wg);
  k_warp<<<256, 128, 0, stream>>>(Fs, Wg, Fea);
  k_logits<<<64, 256, 0, stream>>>(Fea, Wl, lb, xout);
}

// Round 2
// 207.699 us; speedup vs baseline: 1.4159x; 1.4159x over previous
//
#include <hip/hip_runtime.h>
#include <hip/hip_bf16.h>
#include <stdint.h>

// WarpNet: conv_bn_relu(512->384 combined) -> window-distance softmax warp -> 1x1 conv -> log_softmax

typedef float v4f __attribute__((ext_vector_type(4)));
typedef __bf16 v8bf __attribute__((ext_vector_type(8)));
typedef unsigned short u16;
typedef unsigned int u32;
typedef u16 u16x8 __attribute__((ext_vector_type(8)));

// ---------------- workspace layout (bytes) ----------------
constexpr size_t XH_OFF  = 0;                                  // padded NHWC input bf16 [4][66][66][512]
constexpr size_t XH_BYTES = (size_t)4*66*66*512*2;
constexpr size_t WT_OFF  = XH_OFF + XH_BYTES;                  // weights bf16 [9][384][512]
constexpr size_t WT_BYTES = (size_t)9*384*512*2;
constexpr size_t FS_OFF  = WT_OFF + WT_BYTES;                  // clip_emb_s NHWC bf16 [4][68][68][256] (pad2)
constexpr size_t FS_BYTES = (size_t)4*68*68*256*2;
constexpr size_t F2_OFF  = FS_OFF + FS_BYTES;                  // clip_emb2 NHWC f32 [4][68][68][128] (pad2)
constexpr size_t F2_BYTES = (size_t)4*68*68*128*4;
constexpr size_t Y2_OFF  = F2_OFF + F2_BYTES;                  // y2 f32 [2][68][68] (border 1e20, interior 0 then atomics)
constexpr size_t Y2_BYTES = (size_t)2*68*68*4;
constexpr size_t FEA_OFF = Y2_OFF + Y2_BYTES;                  // final_fea bf16 [2][4096][256]
constexpr size_t FEA_BYTES = (size_t)2*4096*256*2;
constexpr size_t WL_OFF  = FEA_OFF + FEA_BYTES;                // last_W bf16 [128][256] (rows 124..127 = 0)
constexpr size_t WL_BYTES = (size_t)128*256*2;
constexpr size_t SC_OFF  = WL_OFF + WL_BYTES;                  // sc[384], bi[384] f32
constexpr size_t WS_TOTAL = SC_OFF + 768*4;

__device__ __forceinline__ float bf2f(u16 h) { return __uint_as_float(((u32)h) << 16); }
__device__ __forceinline__ u16 f2bf(float f) {
  u32 u = __float_as_uint(f);
  return (u16)((u + 0x7fffu + ((u >> 16) & 1u)) >> 16);
}

__device__ __forceinline__ void gld16(const void* g, const void* l) {
  __builtin_amdgcn_global_load_lds(
      (const __attribute__((address_space(1))) void*)(uintptr_t)g,
      (__attribute__((address_space(3))) void*)(u32)(uintptr_t)l,
      16, 0, 0);
}

// ---------------- init: borders, Y2, Wl, sc/bi (fused) ----------------
__global__ void k_init(const float* __restrict__ eg, const float* __restrict__ eb,
                       const float* __restrict__ em, const float* __restrict__ ev,
                       const float* __restrict__ e2g, const float* __restrict__ e2b,
                       const float* __restrict__ e2m, const float* __restrict__ e2v,
                       const float* __restrict__ lw,
                       u16* __restrict__ Xh, u16* __restrict__ Fs, float* __restrict__ F2,
                       float* __restrict__ Y2, u16* __restrict__ Wl,
                       float* __restrict__ sc, float* __restrict__ bi) {
  const u32 N0 = 4u * 260u * 64u;   // Xh border u16x8 chunks
  const u32 N1 = 4u * 528u * 32u;   // Fs border u16x8 chunks
  const u32 N2 = 4u * 528u * 32u;   // F2 border float4 chunks
  const u32 N3 = 2u * 68u * 68u;    // Y2 floats
  const u32 N4 = 4096u;             // Wl u16x8 chunks
  const u32 N5 = 384u;              // sc/bi
  const u32 TOT = N0 + N1 + N2 + N3 + N4 + N5;
  const u16x8 z8 = {0,0,0,0,0,0,0,0};
  for (u32 i = blockIdx.x * 256u + threadIdx.x; i < TOT; i += gridDim.x * 256u) {
    if (i < N0) {
      const u32 img = i / (260u * 64u);
      const u32 rem = i - img * (260u * 64u);
      const u32 r = rem >> 6, ch8 = rem & 63u;
      u32 prow, pcol;
      if (r < 132u) { prow = (r >= 66u) ? 65u : 0u; pcol = r - ((r >= 66u) ? 66u : 0u); }
      else { const u32 rr = r - 132u; prow = 1u + (rr >> 1); pcol = (rr & 1u) * 65u; }
      *(u16x8*)(Xh + ((size_t)((img * 66u + prow) * 66u + pcol)) * 512u + ch8 * 8u) = z8;
    } else if (i < N0 + N1 + N2) {
      const bool isF2 = (i >= N0 + N1);
      const u32 j = isF2 ? (i - N0 - N1) : (i - N0);
      const u32 img = j / (528u * 32u);
      const u32 rem = j - img * (528u * 32u);
      const u32 r = rem >> 5, cg = rem & 31u;
      u32 prow, pcol;
      if (r < 272u) { const u32 q = r / 68u; prow = (q < 2u) ? q : q + 64u; pcol = r - q * 68u; }
      else { const u32 rr = r - 272u; prow = 2u + (rr >> 2); const u32 c = rr & 3u; pcol = (c < 2u) ? c : c + 64u; }
      if (isF2) {
        const float4 zf = {0.f, 0.f, 0.f, 0.f};
        *(float4*)(F2 + ((size_t)((img * 68u + prow) * 68u + pcol)) * 128u + cg * 4u) = zf;
      } else {
        *(u16x8*)(Fs + ((size_t)((img * 68u + prow) * 68u + pcol)) * 256u + cg * 8u) = z8;
      }
    } else if (i < N0 + N1 + N2 + N3) {
      const u32 j = i - N0 - N1 - N2;
      const u32 n = j / 4624u, rc = j - n * 4624u;
      const u32 rr = rc / 68u, cc = rc - rr * 68u;
      const bool interior = (rr >= 2u && rr < 66u && cc >= 2u && cc < 66u);
      Y2[j] = interior ? 0.f : 1e20f;
    } else if (i < N0 + N1 + N2 + N3 + N4) {
      const u32 j = i - N0 - N1 - N2 - N3;
      const u32 row = j >> 5, c8 = (j & 31u) * 8u;
      u16x8 o;
      #pragma unroll
      for (int k = 0; k < 8; ++k) o[k] = (row < 124u) ? f2bf(lw[row * 256u + c8 + k]) : (u16)0;
      *(u16x8*)(Wl + (size_t)row * 256u + c8) = o;
    } else {
      const u32 id = i - N0 - N1 - N2 - N3 - N4;
      float g, b, m, v;
      if (id < 256u) { g = eg[id]; b = eb[id]; m = em[id]; v = ev[id]; }
      else { const u32 q = id - 256u; g = e2g[q]; b = e2b[q]; m = e2m[q]; v = e2v[q]; }
      const float s = g / sqrtf(v + 1e-5f);
      sc[id] = s;
      bi[id] = b - m * s;
    }
  }
}

// ---------------- NCHW f32 -> padded NHWC bf16 ----------------
__global__ __launch_bounds__(256) void k_prep_x(const float* __restrict__ X, u16* __restrict__ Xh) {
  __shared__ __align__(16) float tile[64 * 65];
  const int tid = threadIdx.x;
  const int n = blockIdx.x >> 7;
  const int rem = blockIdx.x & 127;
  const int h = rem >> 1, chalf = rem & 1;
  const int wq = tid >> 6, wcol = tid & 63;
  #pragma unroll 1
  for (int it = 0; it < 4; ++it) {
    const int c0 = chalf * 256 + it * 64;
    __syncthreads();
    #pragma unroll
    for (int i = 0; i < 16; ++i) {
      const int cl = i * 4 + wq;
      tile[cl * 65 + wcol] = X[((size_t)(n * 512 + c0 + cl)) * 4096 + h * 64 + wcol];
    }
    __syncthreads();
    const int w = tid >> 2, cg = tid & 3;
    u16x8 a, b;
    #pragma unroll
    for (int j = 0; j < 8; ++j) a[j] = f2bf(tile[(cg * 16 + j) * 65 + w]);
    #pragma unroll
    for (int j = 0; j < 8; ++j) b[j] = f2bf(tile[(cg * 16 + 8 + j) * 65 + w]);
    u16* dst = Xh + ((size_t)((n * 66 + h + 1) * 66 + (w + 1))) * 512 + c0 + cg * 16;
    *(u16x8*)dst = a;
    *((u16x8*)dst + 1) = b;
  }
}

// ---------------- weights [oc][c][3][3] f32 -> [pos][oc][c] bf16 ----------------
__global__ __launch_bounds__(256) void k_prep_w(const float* __restrict__ embW, const float* __restrict__ emb2W,
                                                u16* __restrict__ Wt) {
  __shared__ float row[4608];
  const int oc = blockIdx.x;
  const int tid = threadIdx.x;
  const float* src = (oc < 256) ? (embW + (size_t)oc * 4608) : (emb2W + (size_t)(oc - 256) * 4608);
  for (int i = tid; i < 4608; i += 256) row[i] = src[i];
  __syncthreads();
  #pragma unroll
  for (int pos = 0; pos < 9; ++pos) {
    const u32 pk = (u32)f2bf(row[(2 * tid) * 9 + pos]) | ((u32)f2bf(row[(2 * tid + 1) * 9 + pos]) << 16);
    *(u32*)(Wt + ((size_t)(pos * 384 + oc)) * 512 + 2 * tid) = pk;
  }
}

// ---------------- implicit-GEMM conv + BN + ReLU (+ y2 atomics) ----------------
// grid 768: octile(6:64oc) x n(4) x pixtile(32:2 rows). tile = 64 oc x 128 px. 4 waves, wave = 64oc x 32px.
// LDS: A 2x4096 [0,8192) | B 2x16896 [8192,41984) | sc/bi [41984,42496)
// XOR swizzle (T2, rule #21): linear gld_lds dest + pre-swizzled global source + swizzled ds_read.
__global__ __launch_bounds__(256) void k_conv(const u16* __restrict__ Xh, const u16* __restrict__ Wt,
                                              const float* __restrict__ sc, const float* __restrict__ bi,
                                              float* __restrict__ out2, float* __restrict__ F2,
                                              u16* __restrict__ Fs, float* __restrict__ Y2) {
  __shared__ __align__(16) char lds[42496];
  const int tid = threadIdx.x;
  const int wvi = tid >> 6, lane = tid & 63;
  const int octile = blockIdx.x >> 7;
  const int rest = blockIdx.x & 127;
  const int n = rest >> 5, pt = rest & 31;
  const int h0 = pt * 2;
  const int oc0 = octile * 64;
  const int pxrow = wvi >> 1;               // output row within the 2-row tile
  const int pxc0 = (wvi & 1) * 32;          // col base of this wave's 32 px

  float* scl = (float*)(lds + 41984);
  float* bil = scl + 64;
  if (tid < 64) { scl[tid] = sc[oc0 + tid]; bil[tid] = bi[oc0 + tid]; }

  // A staging source (per-thread, fixed): LDS row=tid>>2, lds slot=tid&3; global slot = lds^row
  const int arow = tid >> 2;
  const size_t asrc0 = (size_t)(oc0 + arow) * 512 + (((tid & 3) ^ (arow & 3)) << 3);
  // B staging sources: 1056 chunks = 4*256 + 32 tail
  const u16* xbase = Xh + (size_t)n * 66 * 66 * 512;
  int bofs[5];
  #pragma unroll
  for (int k = 0; k < 5; ++k) {
    const int idx = k * 256 + tid;
    if (idx < 1056) {
      const int col = idx >> 2;
      const int ssrc = (idx & 3) ^ (col & 3);
      const int imgrow = col / 66, c = col - imgrow * 66;
      bofs[k] = ((h0 + imgrow) * 66 + c) * 512 + ssrc * 8;
    } else bofs[k] = 0;
  }

  auto stageA = [&](int pos, int cc, int buf) {
    gld16(Wt + (size_t)pos * 384 * 512 + asrc0 + cc * 32, lds + buf * 4096 + wvi * 1024);
  };
  auto stageB = [&](int cc, int buf) {
    char* base = lds + 8192 + buf * 16896;
    #pragma unroll
    for (int k = 0; k < 4; ++k)
      gld16(xbase + bofs[k] + cc * 32, base + k * 4096 + wvi * 1024);
    if (tid < 32) gld16(xbase + bofs[4] + cc * 32, base + 16384);
  };

  v4f acc[4][2];
  #pragma unroll
  for (int mt = 0; mt < 4; ++mt) { acc[mt][0] = (v4f){0,0,0,0}; acc[mt][1] = (v4f){0,0,0,0}; }

  int bA = 0, bB = 0;
  stageB(0, 0);
  stageA(0, 0, 0);
  __syncthreads();

  #pragma unroll 1
  for (int cc = 0; cc < 16; ++cc) {
    #pragma unroll
    for (int pos = 0; pos < 9; ++pos) {
      const int ky = pos / 3, kx = pos % 3;
      if (pos < 8) {
        stageA(pos + 1, cc, bA ^ 1);
      } else if (cc < 15) {
        stageB(cc + 1, bB ^ 1);
        stageA(0, cc + 1, bA ^ 1);
      }
      v8bf af[4], bfr[2];
      const char* pA = lds + bA * 4096 + ((lane & 15) << 6) + ((((lane >> 4) ^ (lane & 3))) << 4);
      #pragma unroll
      for (int mt = 0; mt < 4; ++mt) af[mt] = *(const v8bf*)(pA + mt * 1024);
      #pragma unroll
      for (int nt = 0; nt < 2; ++nt) {
        const int rb = (pxrow + ky) * 66 + pxc0 + nt * 16 + (lane & 15) + kx;
        bfr[nt] = *(const v8bf*)(lds + 8192 + bB * 16896 + (rb << 6) + (((lane >> 4) ^ (rb & 3)) << 4));
      }
      #pragma unroll
      for (int mt = 0; mt < 4; ++mt)
        #pragma unroll
        for (int nt = 0; nt < 2; ++nt)
          acc[mt][nt] = __builtin_amdgcn_mfma_f32_16x16x32_bf16(af[mt], bfr[nt], acc[mt][nt], 0, 0, 0);
      __syncthreads();
      bA ^= 1;
      if (pos == 8) bB ^= 1;
    }
  }

  // BN + ReLU
  float vals[4][2][4];
  #pragma unroll
  for (int mt = 0; mt < 4; ++mt) {
    const int ocb = mt * 16 + ((lane >> 4) << 2);
    #pragma unroll
    for (int j = 0; j < 4; ++j) {
      const float s = scl[ocb + j], tt = bil[ocb + j];
      #pragma unroll
      for (int nt = 0; nt < 2; ++nt) vals[mt][nt][j] = fmaxf(fmaf(acc[mt][nt][j], s, tt), 0.f);
    }
  }

  if (octile >= 4) {
    // emb2 (oc 256..383): NCHW f32 to d_out + y2 atomics + NHWC f32 to F2
    #pragma unroll
    for (int mt = 0; mt < 4; ++mt)
      #pragma unroll
      for (int j = 0; j < 4; ++j) {
        const int oc = (octile - 4) * 64 + mt * 16 + ((lane >> 4) << 2) + j;
        float* orow = out2 + ((size_t)(n * 128 + oc)) * 4096 + (h0 + pxrow) * 64 + pxc0;
        orow[(lane & 15)] = vals[mt][0][j];
        orow[16 + (lane & 15)] = vals[mt][1][j];
      }
    if (n < 2) {
      #pragma unroll
      for (int nt = 0; nt < 2; ++nt) {
        float s = 0.f;
        #pragma unroll
        for (int mt = 0; mt < 4; ++mt)
          #pragma unroll
          for (int j = 0; j < 4; ++j) s = fmaf(vals[mt][nt][j], vals[mt][nt][j], s);
        s += __shfl_xor(s, 16);
        s += __shfl_xor(s, 32);
        if ((lane >> 4) == 0)
          atomicAdd(&Y2[(size_t)(n * 68 + h0 + pxrow + 2) * 68 + pxc0 + nt * 16 + (lane & 15) + 2], s);
      }
    }
    float* T = (float*)lds;  // [128 px][64 oc] f32 = 32KB
    #pragma unroll
    for (int mt = 0; mt < 4; ++mt)
      #pragma unroll
      for (int nt = 0; nt < 2; ++nt)
        #pragma unroll
        for (int j = 0; j < 4; ++j)
          T[(wvi * 32 + nt * 16 + (lane & 15)) * 64 + mt * 16 + ((lane >> 4) << 2) + j] = vals[mt][nt][j];
    __syncthreads();
    const int px = tid >> 1, half = tid & 1;
    const float4* Tp = (const float4*)(T + px * 64 + half * 32);
    float4* dst = (float4*)(F2 + ((size_t)((n * 68 + h0 + (px >> 6) + 2) * 68 + (px & 63) + 2)) * 128 + (octile - 4) * 64 + half * 32);
    #pragma unroll
    for (int i = 0; i < 8; ++i) dst[i] = Tp[i];
  } else {
    // emb (oc 0..255): NHWC bf16 to Fs
    u16* T = (u16*)lds;  // [128 px][64 oc] bf16 = 16KB
    #pragma unroll
    for (int mt = 0; mt < 4; ++mt)
      #pragma unroll
      for (int nt = 0; nt < 2; ++nt)
        #pragma unroll
        for (int jj = 0; jj < 2; ++jj) {
          const u32 pk = (u32)f2bf(vals[mt][nt][2 * jj]) | ((u32)f2bf(vals[mt][nt][2 * jj + 1]) << 16);
          *(u32*)(T + (wvi * 32 + nt * 16 + (lane & 15)) * 64 + mt * 16 + ((lane >> 4) << 2) + 2 * jj) = pk;
        }
    __syncthreads();
    const int px = tid >> 1, half = tid & 1;
    const u16x8* Tp = (const u16x8*)(T + px * 64 + half * 32);
    u16x8* dst = (u16x8*)(Fs + ((size_t)((n * 68 + h0 + (px >> 6) + 2) * 68 + (px & 63) + 2)) * 256 + octile * 64 + half * 32);
    #pragma unroll
    for (int i = 0; i < 4; ++i) dst[i] = Tp[i];
  }
}

// ---------------- fused distance + softmax + warp -> fea (L2-direct, no LDS) ----------------
// 8 threads per pixel. grid 256 x 256 = 65536 = 8192 px x 8.
__global__ __launch_bounds__(256) void k_dw(const float* __restrict__ F2, const float* __restrict__ Y2,
                                            const u16* __restrict__ Fs, u16* __restrict__ Fea) {
  const int t = blockIdx.x * 256 + threadIdx.x;
  const int g = t & 7;
  const int px = t >> 3;
  const int n = px >> 12;
  const int p = px & 4095;
  const int h = p >> 6, w = p & 63;

  // phase 1: distances over 16 channels (g*16) of F2, reduce over 8 lanes
  const float4* c2p = (const float4*)(F2 + ((size_t)(((n + 2) * 68 + h + 2) * 68 + (w + 2))) * 128 + g * 16);
  float4 c2v[4];
  float x2 = 0.f;
  #pragma unroll
  for (int i = 0; i < 4; ++i) {
    c2v[i] = c2p[i];
    x2 += c2v[i].x * c2v[i].x + c2v[i].y * c2v[i].y + c2v[i].z * c2v[i].z + c2v[i].w * c2v[i].w;
  }
  float cross[25];
  #pragma unroll
  for (int dy = 0; dy < 5; ++dy) {
    const float* rowp = F2 + ((size_t)((n * 68 + h + dy) * 68 + w)) * 128 + g * 16;
    #pragma unroll
    for (int dx = 0; dx < 5; ++dx) {
      const float4* wp = (const float4*)(rowp + dx * 128);
      float s = 0.f;
      #pragma unroll
      for (int i = 0; i < 4; ++i) {
        const float4 u = wp[i];
        s += c2v[i].x * u.x + c2v[i].y * u.y + c2v[i].z * u.z + c2v[i].w * u.w;
      }
      cross[dy * 5 + dx] = s;
    }
  }
  x2 += __shfl_xor(x2, 1); x2 += __shfl_xor(x2, 2); x2 += __shfl_xor(x2, 4);
  #pragma unroll
  for (int o = 0; o < 25; ++o) {
    cross[o] += __shfl_xor(cross[o], 1);
    cross[o] += __shfl_xor(cross[o], 2);
    cross[o] += __shfl_xor(cross[o], 4);
  }
  float wv[25], mx = -1e30f;
  #pragma unroll
  for (int dy = 0; dy < 5; ++dy)
    #pragma unroll
    for (int dx = 0; dx < 5; ++dx) {
      const int o = dy * 5 + dx;
      const float y2v = Y2[(size_t)(n * 68 + h + dy) * 68 + (w + dx)];
      const float dist = x2 + y2v - 2.f * cross[o];
      const float l = 1.f / (dist + 1e-5f);
      wv[o] = l;
      mx = fmaxf(mx, l);
    }
  float ssum = 0.f;
  #pragma unroll
  for (int o = 0; o < 25; ++o) { const float e = __expf(wv[o] - mx); wv[o] = e; ssum += e; }
  const float inv = 1.f / ssum;
  #pragma unroll
  for (int o = 0; o < 25; ++o) wv[o] *= inv;

  // phase 2: warp over 32 channels (g*32) of Fs
  float facc[32];
  #pragma unroll
  for (int i = 0; i < 32; ++i) facc[i] = 0.f;
  #pragma unroll
  for (int dy = 0; dy < 5; ++dy) {
    const u16* rp = Fs + ((size_t)((n * 68 + h + dy) * 68 + w)) * 256 + g * 32;
    #pragma unroll
    for (int dx = 0; dx < 5; ++dx) {
      const float wt = wv[dy * 5 + dx];
      const u16x8* up = (const u16x8*)(rp + dx * 256);
      #pragma unroll
      for (int k = 0; k < 4; ++k) {
        const u16x8 u = up[k];
        #pragma unroll
        for (int j = 0; j < 8; ++j) facc[k * 8 + j] = fmaf(wt, bf2f(u[j]), facc[k * 8 + j]);
      }
    }
  }
  const u16x8* cip = (const u16x8*)(Fs + ((size_t)(((n + 2) * 68 + h + 2) * 68 + (w + 2))) * 256 + g * 32);
  u16x8* dp = (u16x8*)(Fea + ((size_t)(n * 4096 + p)) * 256 + g * 32);
  #pragma unroll
  for (int k = 0; k < 4; ++k) {
    const u16x8 cu = cip[k];
    u16x8 ou;
    #pragma unroll
    for (int j = 0; j < 8; ++j)
      ou[j] = f2bf(0.5f * (bf2f(cu[j]) + facc[k * 8 + j] * (1.f / 25.f)));
    dp[k] = ou;
  }
}

// ---------------- logits (124x256 via MFMA) + log_softmax. 256 blocks x 128 thr, wave = 16 px ----------------
__global__ __launch_bounds__(128) void k_logits(const u16* __restrict__ Fea, const u16* __restrict__ Wl,
                                                const float* __restrict__ lb, float* __restrict__ xout) {
  const int wvi = threadIdx.x >> 6, lane = threadIdx.x & 63;
  const int wid = blockIdx.x * 2 + wvi;
  const int n = wid >> 8;
  const int p0 = (wid & 255) * 16;
  const int lp = lane & 15;
  const int kb = (lane >> 4) * 8;

  v4f acc[8];
  #pragma unroll
  for (int mt = 0; mt < 8; ++mt) acc[mt] = (v4f){0.f, 0.f, 0.f, 0.f};

  #pragma unroll
  for (int kc = 0; kc < 8; ++kc) {
    const v8bf b = *(const v8bf*)(Fea + ((size_t)(n * 4096 + p0 + lp)) * 256 + kc * 32 + kb);
    #pragma unroll
    for (int mt = 0; mt < 8; ++mt) {
      const v8bf a = *(const v8bf*)(Wl + ((size_t)(mt * 16 + lp)) * 256 + kc * 32 + kb);
      acc[mt] = __builtin_amdgcn_mfma_f32_16x16x32_bf16(a, b, acc[mt], 0, 0, 0);
    }
  }
  const int r0 = (lane >> 4) * 4;
  float v[8][4];
  float mx = -1e30f;
  #pragma unroll
  for (int mt = 0; mt < 8; ++mt)
    #pragma unroll
    for (int j = 0; j < 4; ++j) {
      const int cls = mt * 16 + r0 + j;
      const float val = (cls < 124) ? (acc[mt][j] + lb[cls]) : -1e30f;
      v[mt][j] = val;
      mx = fmaxf(mx, val);
    }
  mx = fmaxf(mx, __shfl_xor(mx, 16));
  mx = fmaxf(mx, __shfl_xor(mx, 32));
  float s = 0.f;
  #pragma unroll
  for (int mt = 0; mt < 8; ++mt)
    #pragma unroll
    for (int j = 0; j < 4; ++j) {
      const int cls = mt * 16 + r0 + j;
      if (cls < 124) s += __expf(v[mt][j] - mx);
    }
  s += __shfl_xor(s, 16);
  s += __shfl_xor(s, 32);
  const float lz = mx + logf(s);
  #pragma unroll
  for (int mt = 0; mt < 8; ++mt)
    #pragma unroll
    for (int j = 0; j < 4; ++j) {
      const int cls = mt * 16 + r0 + j;
      if (cls < 124)
        xout[((size_t)(n * 124 + cls)) * 4096 + p0 + lp] = v[mt][j] - lz;
    }
}

extern "C" void kernel_launch(void* const* d_in, const int* in_sizes, int n_in,
                              void* d_out, int out_size, void* d_ws, size_t ws_size,
                              hipStream_t stream) {
  (void)in_sizes; (void)n_in; (void)out_size;
  const float* clip  = (const float*)d_in[0];
  const float* embW  = (const float*)d_in[2];
  const float* eg    = (const float*)d_in[3];
  const float* eb    = (const float*)d_in[4];
  const float* em    = (const float*)d_in[5];
  const float* ev    = (const float*)d_in[6];
  const float* emb2W = (const float*)d_in[7];
  const float* e2g   = (const float*)d_in[8];
  const float* e2b   = (const float*)d_in[9];
  const float* e2m   = (const float*)d_in[10];
  const float* e2v   = (const float*)d_in[11];
  const float* lw    = (const float*)d_in[12];
  const float* lb    = (const float*)d_in[13];

  char* ws = (char*)d_ws;
  u16*   Xh  = (u16*)(ws + XH_OFF);
  u16*   Wt  = (u16*)(ws + WT_OFF);
  u16*   Fs  = (u16*)(ws + FS_OFF);
  float* F2  = (float*)(ws + F2_OFF);
  float* Y2  = (float*)(ws + Y2_OFF);
  u16*   Fea = (u16*)(ws + FEA_OFF);
  u16*   Wl  = (u16*)(ws + WL_OFF);
  float* sc  = (float*)(ws + SC_OFF);
  float* bi  = sc + 384;

  float* xout = (float*)d_out;
  float* out2 = xout + (size_t)2 * 124 * 64 * 64;

  if (ws_size < WS_TOTAL) return;

  k_init<<<256, 256, 0, stream>>>(eg, eb, em, ev, e2g, e2b, e2m, e2v, lw, Xh, Fs, F2, Y2, Wl, sc, bi);
  k_prep_x<<<512, 256, 0, stream>>>(clip, Xh);
  k_prep_w<<<384, 256, 0, stream>>>(embW, emb2W, Wt);
  k_conv<<<768, 256, 0, stream>>>(Xh, Wt, sc, bi, out2, F2, Fs, Y2);
  k_dw<<<256, 256, 0, stream>>>(F2, Y2, Fs, Fea);
  k_logits<<<256, 128, 0, stream>>>(Fea, Wl, lb, xout);
}